// Round 1
// baseline (198.101 us; speedup 1.0000x reference)
//
#include <hip/hip_runtime.h>
#include <hip/hip_bf16.h>

// Problem constants (from reference): B=16, T=12, N=1024, F_IN=F_OUT=64, K=3
#define BB 16
#define TT 12
#define NN 1024
#define FF 64
#define KC 3

// Tile: BM=64 (i), BN=256 (4 t * 64 f), BK=64 (j), 512 threads = 8 waves
// Waves: wm = wid>>1 (0..3) -> c-block of 64 (t_local = wm); wn = wid&1 -> i half (32)

typedef __bf16 bf16x8 __attribute__((ext_vector_type(8)));
typedef float  f32x4  __attribute__((ext_vector_type(4)));
typedef float  f32x16 __attribute__((ext_vector_type(16)));

// LDS geometry (bf16 elements), row pad to 72 (144B, 16B-aligned rows)
#define A_ROWS 64
#define A_PAD  72
#define X_ROWS 256
#define X_PAD  72
#define A_BYTES (KC * A_ROWS * A_PAD * 2)        // 27648
#define X_BYTES (X_ROWS * X_PAD * 2)             // 36864 (Theta frags overlaid later: 24*64*8*2=24576)

__global__ __launch_bounds__(512, 2) void cheb_fused(
    const float* __restrict__ x,      // [B,T,N,F]
    const float* __restrict__ att,    // [B,N,N]
    const float* __restrict__ cheb,   // [K,N,N]
    const float* __restrict__ Theta,  // [K,F,F]
    float* __restrict__ out)          // [B,T,N,F]
{
    __shared__ __align__(16) char lds_raw[A_BYTES + X_BYTES];   // 64512 B
    __bf16* Abase = reinterpret_cast<__bf16*>(lds_raw);
    __bf16* Xbase = reinterpret_cast<__bf16*>(lds_raw + A_BYTES);
    // A_lds[k][i][j] : Abase[(k*A_ROWS + i)*A_PAD + j]
    // X_lds[c][j]    : Xbase[c*X_PAD + j]
    // Th_lds[fi][lane][e] (overlay on X after main loop): Xbase[(fi*64 + lane)*8 + e]

    const int tid  = threadIdx.x;
    const int lane = tid & 63;
    const int wid  = tid >> 6;
    const int bid  = blockIdx.x;

    const int b  = bid / 48;
    const int it = (bid % 48) / 3;
    const int tc = bid % 3;
    const int i_base = it * 64;
    const int t_base = tc * 4;

    const int wm = wid >> 1;   // 0..3 : c block (t_local)
    const int wn = wid & 1;    // 0..1 : i half
    const int l31 = lane & 31;
    const int lg  = lane >> 5; // 0..1

    const float* attB = att + (size_t)b * NN * NN;
    const float* xB   = x + (size_t)b * TT * NN * FF;

    f32x16 acc[KC][2] = {};    // acc[k][m]: rhsT[c = wm*64+m*32+row][i = wn*32+l31]

    for (int jt = 0; jt < NN / 64; ++jt) {
        const int j0 = jt * 64;
        __syncthreads();   // previous iter's fragment reads complete

        // ---- stage A = cheb*att (bf16) : 64 rows x 64 j, all K ----
        {
            const int r = tid >> 3;        // 0..63
            const int g = tid & 7;         // col group: j = g*8 .. g*8+7
            const float* ap = attB + (size_t)(i_base + r) * NN + j0 + g * 8;
            f32x4 a0 = *reinterpret_cast<const f32x4*>(ap);
            f32x4 a1 = *reinterpret_cast<const f32x4*>(ap + 4);
            #pragma unroll
            for (int k = 0; k < KC; ++k) {
                const float* cp = cheb + ((size_t)k * NN + i_base + r) * NN + j0 + g * 8;
                f32x4 c0 = *reinterpret_cast<const f32x4*>(cp);
                f32x4 c1 = *reinterpret_cast<const f32x4*>(cp + 4);
                bf16x8 w;
                #pragma unroll
                for (int e = 0; e < 4; ++e) {
                    w[e]     = (__bf16)(c0[e] * a0[e]);
                    w[e + 4] = (__bf16)(c1[e] * a1[e]);
                }
                *reinterpret_cast<bf16x8*>(&Abase[(k * A_ROWS + r) * A_PAD + g * 8]) = w;
            }
        }

        // ---- stage X transposed: X_lds[c = tl*64+f][j], 4 t x 64 j x 64 f ----
        #pragma unroll
        for (int s = 0; s < 4; ++s) {
            int u   = tid + s * 512;        // 0..2047 "pair" index
            int tl  = u >> 9;               // 0..3
            int rem = u & 511;
            int jj  = (rem >> 4) * 2;       // even j
            int f   = (rem & 15) * 4;
            const float* xp = xB + ((size_t)(t_base + tl) * NN + j0 + jj) * FF + f;
            f32x4 v0 = *reinterpret_cast<const f32x4*>(xp);
            f32x4 v1 = *reinterpret_cast<const f32x4*>(xp + FF);
            #pragma unroll
            for (int e = 0; e < 4; ++e) {
                union { __bf16 h[2]; unsigned u32; } pk;
                pk.h[0] = (__bf16)v0[e];
                pk.h[1] = (__bf16)v1[e];
                *reinterpret_cast<unsigned*>(&Xbase[(tl * 64 + f + e) * X_PAD + jj]) = pk.u32;
            }
        }
        __syncthreads();

        // ---- MFMA: rhsT[c][i] += sum_j Xt[c][j] * A_k[i][j] ----
        #pragma unroll
        for (int kk = 0; kk < 4; ++kk) {
            const int jf = kk * 16 + 8 * lg;    // slot base (same map for both operands)
            bf16x8 afrag[2];
            #pragma unroll
            for (int m = 0; m < 2; ++m)
                afrag[m] = *reinterpret_cast<const bf16x8*>(
                    &Xbase[(wm * 64 + m * 32 + l31) * X_PAD + jf]);
            #pragma unroll
            for (int k = 0; k < KC; ++k) {
                bf16x8 bfrag = *reinterpret_cast<const bf16x8*>(
                    &Abase[(k * A_ROWS + wn * 32 + l31) * A_PAD + jf]);
                #pragma unroll
                for (int m = 0; m < 2; ++m)
                    acc[k][m] = __builtin_amdgcn_mfma_f32_32x32x16_bf16(
                        afrag[m], bfrag, acc[k][m], 0, 0, 0);
            }
        }
    }

    // ---- stage Theta fragments into X region (A-operand of epilogue) ----
    // frag fi = (k*2+mo)*4+s ; slot (g=lane>>5, e) holds Theta[k][f][o],
    // f = 32*(s>>1) + 16*(s&1) + (e&3) + 8*(e>>2) + 4*g ; o = 32*mo + l31
    __syncthreads();   // main-loop X reads done before overlay
    {
        const int fi0 = wid * 3;
        #pragma unroll
        for (int q = 0; q < 3; ++q) {
            int fi = fi0 + q;
            int k  = fi >> 3;
            int mo = (fi >> 2) & 1;
            int s  = fi & 3;
            int o  = 32 * mo + l31;
            int fb = 32 * (s >> 1) + 16 * (s & 1) + 4 * lg;
            bf16x8 v;
            #pragma unroll
            for (int e = 0; e < 8; ++e) {
                int f = fb + (e & 3) + 8 * (e >> 2);
                v[e] = (__bf16)Theta[(k * FF + f) * FF + o];
            }
            *reinterpret_cast<bf16x8*>(&Xbase[(fi * 64 + lane) * 8]) = v;
        }
    }
    __syncthreads();

    // ---- epilogue: out^T[o][i] = sum_{k,f} Theta^T[o][f] * rhsT[f][i], via MFMA ----
    // B-operand comes straight from acc: slot (g,e) of step s <- acc[k][s>>1][e + 8*(s&1)]
    f32x16 of[2] = {};
    #pragma unroll
    for (int k = 0; k < KC; ++k) {
        #pragma unroll
        for (int s = 0; s < 4; ++s) {
            bf16x8 pb;
            #pragma unroll
            for (int e = 0; e < 8; ++e)
                pb[e] = (__bf16)acc[k][s >> 1][e + 8 * (s & 1)];
            #pragma unroll
            for (int mo = 0; mo < 2; ++mo) {
                bf16x8 th = *reinterpret_cast<const bf16x8*>(
                    &Xbase[(((k * 2 + mo) * 4 + s) * 64 + lane) * 8]);
                of[mo] = __builtin_amdgcn_mfma_f32_32x32x16_bf16(th, pb, of[mo], 0, 0, 0);
            }
        }
    }

    // ---- write out[b, t, i, o] = relu(of[mo][r]) ----
    const int t = t_base + wm;
    const int i = i_base + wn * 32 + l31;
    float* op = out + (((size_t)b * TT + t) * NN + i) * FF;
    #pragma unroll
    for (int mo = 0; mo < 2; ++mo) {
        #pragma unroll
        for (int r = 0; r < 16; ++r) {
            int o = 32 * mo + (r & 3) + 8 * (r >> 2) + 4 * lg;
            float v = of[mo][r];
            op[o] = v > 0.0f ? v : 0.0f;
        }
    }
}

extern "C" void kernel_launch(void* const* d_in, const int* in_sizes, int n_in,
                              void* d_out, int out_size, void* d_ws, size_t ws_size,
                              hipStream_t stream) {
    const float* x     = (const float*)d_in[0];
    const float* att   = (const float*)d_in[1];
    const float* cheb  = (const float*)d_in[2];
    const float* Theta = (const float*)d_in[3];
    float* out = (float*)d_out;
    (void)d_ws; (void)ws_size; (void)in_sizes; (void)n_in; (void)out_size;

    dim3 grid(BB * (NN / 64) * (TT / 4));   // 16 * 16 * 3 = 768 blocks
    cheb_fused<<<grid, 512, 0, stream>>>(x, att, cheb, Theta, out);
}

// Round 2
// 128.456 us; speedup vs baseline: 1.5422x; 1.5422x over previous
//
#include <hip/hip_runtime.h>
#include <hip/hip_bf16.h>

// B=16, T=12, N=1024, F_IN=F_OUT=64, K=3
#define BB 16
#define TT 12
#define NN 1024
#define FF 64
#define KC 3

typedef __bf16 bf16x8 __attribute__((ext_vector_type(8)));
typedef float  f32x4  __attribute__((ext_vector_type(4)));
typedef float  f32x16 __attribute__((ext_vector_type(16)));

// LDS: unpadded 128-byte rows (64 bf16), XOR-swizzled with ((row>>2)&7)<<4
#define A_BYTES (KC * 64 * 128)   // 24576
#define X_BYTES (256 * 128)       // 32768 (Theta frags overlaid later: 24*64*16 = 24576)

__global__ __launch_bounds__(512, 2) void cheb_fused(
    const float* __restrict__ x,      // [B,T,N,F]
    const float* __restrict__ att,    // [B,N,N]
    const float* __restrict__ cheb,   // [K,N,N]
    const float* __restrict__ Theta,  // [K,F,F]
    float* __restrict__ out)          // [B,T,N,F]
{
    __shared__ __align__(16) char lds_raw[A_BYTES + X_BYTES];   // 57344 B
    char* Ab = lds_raw;
    char* Xb = lds_raw + A_BYTES;

    const int tid  = threadIdx.x;
    const int lane = tid & 63;
    const int wid  = tid >> 6;

    // XCD-aware bijective swizzle: 768 blocks, 8 XCDs, chunk = 96 (= 2 b's)
    const int wg = (blockIdx.x & 7) * 96 + (blockIdx.x >> 3);
    const int b  = wg / 48;
    const int it = (wg % 48) / 3;
    const int tc = wg % 3;
    const int i_base = it * 64;
    const int t_base = tc * 4;

    const int wm  = wid >> 1;   // 0..3 : t_local
    const int wn  = wid & 1;    // 0..1 : i half
    const int l31 = lane & 31;
    const int lg  = lane >> 5;
    const int sw3 = (l31 >> 2) & 7;     // fragment-read swizzle (16B units)

    const float* attB = att + (size_t)b * NN * NN;
    const float* xB   = x + (size_t)b * TT * NN * FF;

    // --- staging index constants (hoisted) ---
    const int r_a = tid >> 3;           // A row 0..63
    const int g_a = tid & 7;            // A col-group (8 j each)
    const int swza_st = ((r_a >> 2) & 7) << 4;
    int tl_s[4], jj_s[4], f_s[4], swzx_st[4];
    #pragma unroll
    for (int s = 0; s < 4; ++s) {
        int u   = tid + s * 512;
        tl_s[s] = u >> 9;
        int rem = u & 511;
        jj_s[s] = (rem >> 4) * 2;       // even j
        f_s[s]  = (rem & 15) * 4;
        swzx_st[s] = ((f_s[s] >> 2) & 7) << 4;
    }

    // --- prefetch registers (tile staged in regs one iteration ahead) ---
    f32x4 ra0, ra1, rc0[KC], rc1[KC], rx0[4], rx1[4];

    auto load_tile = [&](int j0) {
        const float* ap = attB + (size_t)(i_base + r_a) * NN + j0 + g_a * 8;
        ra0 = *reinterpret_cast<const f32x4*>(ap);
        ra1 = *reinterpret_cast<const f32x4*>(ap + 4);
        #pragma unroll
        for (int k = 0; k < KC; ++k) {
            const float* cp = cheb + ((size_t)k * NN + i_base + r_a) * NN + j0 + g_a * 8;
            rc0[k] = *reinterpret_cast<const f32x4*>(cp);
            rc1[k] = *reinterpret_cast<const f32x4*>(cp + 4);
        }
        #pragma unroll
        for (int s = 0; s < 4; ++s) {
            const float* xp = xB + ((size_t)(t_base + tl_s[s]) * NN + j0 + jj_s[s]) * FF + f_s[s];
            rx0[s] = *reinterpret_cast<const f32x4*>(xp);
            rx1[s] = *reinterpret_cast<const f32x4*>(xp + FF);
        }
    };

    f32x16 acc[KC][2] = {};    // acc[k][m]: rhsT[c = wm*64+m*32+row][i = wn*32+l31]

    load_tile(0);
    for (int jt = 0; jt < NN / 64; ++jt) {
        __syncthreads();   // previous iter's fragment reads complete

        // ---- store A = cheb*att (bf16, swizzled b128 writes, 2-way) ----
        #pragma unroll
        for (int k = 0; k < KC; ++k) {
            bf16x8 w;
            #pragma unroll
            for (int e = 0; e < 4; ++e) {
                w[e]     = (__bf16)(rc0[k][e] * ra0[e]);
                w[e + 4] = (__bf16)(rc1[k][e] * ra1[e]);
            }
            *reinterpret_cast<bf16x8*>(Ab + (k * 64 + r_a) * 128 + ((g_a * 16) ^ swza_st)) = w;
        }
        // ---- store X^T (bf16 pairs, swizzled 4B writes, 2-way) ----
        #pragma unroll
        for (int s = 0; s < 4; ++s) {
            const int c0     = tl_s[s] * 64 + f_s[s];
            const int coloff = (jj_s[s] * 2) ^ swzx_st[s];
            #pragma unroll
            for (int e = 0; e < 4; ++e) {
                union { __bf16 h[2]; unsigned u32; } pk;
                pk.h[0] = (__bf16)rx0[s][e];
                pk.h[1] = (__bf16)rx1[s][e];
                *reinterpret_cast<unsigned*>(Xb + (c0 + e) * 128 + coloff) = pk.u32;
            }
        }
        __syncthreads();

        if (jt + 1 < NN / 64) load_tile((jt + 1) * 64);   // prefetch under MFMA

        // ---- MFMA: rhsT[c][i] += sum_j Xt[c][j] * A_k[i][j] ----
        const int xrow0 = (wm * 64 + l31) * 128;
        const int xrow1 = xrow0 + 32 * 128;
        const int arow  = (wn * 32 + l31) * 128;
        #pragma unroll
        for (int kk = 0; kk < 4; ++kk) {
            const int off = ((kk * 2 + lg) ^ sw3) << 4;   // swizzled 16B column
            bf16x8 af0 = *reinterpret_cast<const bf16x8*>(Xb + xrow0 + off);
            bf16x8 af1 = *reinterpret_cast<const bf16x8*>(Xb + xrow1 + off);
            #pragma unroll
            for (int k = 0; k < KC; ++k) {
                bf16x8 bf = *reinterpret_cast<const bf16x8*>(Ab + k * 64 * 128 + arow + off);
                acc[k][0] = __builtin_amdgcn_mfma_f32_32x32x16_bf16(af0, bf, acc[k][0], 0, 0, 0);
                acc[k][1] = __builtin_amdgcn_mfma_f32_32x32x16_bf16(af1, bf, acc[k][1], 0, 0, 0);
            }
        }
    }

    // ---- stage Theta fragments into X region ----
    __syncthreads();
    {
        const int fi0 = wid * 3;
        #pragma unroll
        for (int q = 0; q < 3; ++q) {
            int fi = fi0 + q;
            int k  = fi >> 3;
            int mo = (fi >> 2) & 1;
            int s  = fi & 3;
            int o  = 32 * mo + l31;
            int fb = 32 * (s >> 1) + 16 * (s & 1) + 4 * lg;
            bf16x8 v;
            #pragma unroll
            for (int e = 0; e < 8; ++e) {
                int f = fb + (e & 3) + 8 * (e >> 2);
                v[e] = (__bf16)Theta[(k * FF + f) * FF + o];
            }
            *reinterpret_cast<bf16x8*>(Xb + (fi * 64 + lane) * 16) = v;
        }
    }
    __syncthreads();

    // ---- epilogue: out[i][o] = sum_{k,f} rhsT[f][i]^T * Theta  (operands swapped
    // vs R1 so D: row=i, col=o -> coalesced stores) ----
    f32x16 of[2] = {};
    #pragma unroll
    for (int k = 0; k < KC; ++k) {
        #pragma unroll
        for (int s = 0; s < 4; ++s) {
            bf16x8 pb;
            #pragma unroll
            for (int e = 0; e < 8; ++e)
                pb[e] = (__bf16)acc[k][s >> 1][e + 8 * (s & 1)];
            #pragma unroll
            for (int mo = 0; mo < 2; ++mo) {
                bf16x8 th = *reinterpret_cast<const bf16x8*>(
                    Xb + ((((k * 2 + mo) * 4 + s) * 64) + lane) * 16);
                of[mo] = __builtin_amdgcn_mfma_f32_32x32x16_bf16(pb, th, of[mo], 0, 0, 0);
            }
        }
    }

    // ---- write out[b, t, i, o] = relu(...), o = lane -> 128B coalesced ----
    const int t = t_base + wm;
    float* op = out + (((size_t)b * TT + t) * NN + i_base + wn * 32) * FF;
    #pragma unroll
    for (int mo = 0; mo < 2; ++mo) {
        #pragma unroll
        for (int r = 0; r < 16; ++r) {
            int row = (r & 3) + 8 * (r >> 2) + 4 * lg;   // i-local 0..31
            int o   = 32 * mo + l31;
            float v = of[mo][r];
            op[(size_t)row * FF + o] = v > 0.0f ? v : 0.0f;
        }
    }
}

extern "C" void kernel_launch(void* const* d_in, const int* in_sizes, int n_in,
                              void* d_out, int out_size, void* d_ws, size_t ws_size,
                              hipStream_t stream) {
    const float* x     = (const float*)d_in[0];
    const float* att   = (const float*)d_in[1];
    const float* cheb  = (const float*)d_in[2];
    const float* Theta = (const float*)d_in[3];
    float* out = (float*)d_out;
    (void)d_ws; (void)ws_size; (void)in_sizes; (void)n_in; (void)out_size;

    dim3 grid(BB * (NN / 64) * (TT / 4));   // 768 blocks
    cheb_fused<<<grid, 512, 0, stream>>>(x, att, cheb, Theta, out);
}

// Round 3
// 127.106 us; speedup vs baseline: 1.5586x; 1.0106x over previous
//
#include <hip/hip_runtime.h>
#include <hip/hip_bf16.h>

// B=16, T=12, N=1024, F_IN=F_OUT=64, K=3
#define BB 16
#define TT 12
#define NN 1024
#define FF 64
#define KC 3

typedef __bf16 bf16x8 __attribute__((ext_vector_type(8)));
typedef float  f32x4  __attribute__((ext_vector_type(4)));
typedef float  f32x16 __attribute__((ext_vector_type(16)));

#define A_TILE 24576   // 3 * 64 * 128 B
#define X_TILE 32768   // 256 * 128 B

#define MFMA_B(a, b, c) __builtin_amdgcn_mfma_f32_32x32x16_bf16(a, b, c, 0, 0, 0)

__global__ __launch_bounds__(512, 2) void cheb_fused(
    const float* __restrict__ x,      // [B,T,N,F]
    const float* __restrict__ att,    // [B,N,N]
    const float* __restrict__ cheb,   // [K,N,N]
    const float* __restrict__ Theta,  // [K,F,F]
    float* __restrict__ out)          // [B,T,N,F]
{
    // Double-buffered: [A0 | X0 | A1 | X1]  (gfx950 LDS limit 160 KB)
    __shared__ __align__(16) char lds_raw[2 * (A_TILE + X_TILE)];   // 114688 B
    char* Ab0 = lds_raw;
    char* Xb0 = lds_raw + A_TILE;
    char* Ab1 = lds_raw + A_TILE + X_TILE;
    char* Xb1 = Ab1 + A_TILE;

    const int tid  = threadIdx.x;
    const int lane = tid & 63;
    const int wid  = tid >> 6;

    // XCD-aware bijective swizzle: 768 blocks % 8 == 0, chunk = 96
    const int wg = (blockIdx.x & 7) * 96 + (blockIdx.x >> 3);
    const int b  = wg / 48;
    const int it = (wg % 48) / 3;
    const int tc = wg % 3;
    const int i_base = it * 64;
    const int t_base = tc * 4;

    const int wm  = wid >> 1;   // 0..3 : t_local
    const int wn  = wid & 1;    // 0..1 : i half
    const int l31 = lane & 31;
    const int lg  = lane >> 5;
    const int sw3 = (l31 >> 2) & 7;

    const float* attB = att + (size_t)b * NN * NN;
    const float* xB   = x + (size_t)b * TT * NN * FF;

    // staging index constants
    const int r_a = tid >> 3;
    const int g_a = tid & 7;
    const int swza_st = ((r_a >> 2) & 7) << 4;
    int tl_s[4], jj_s[4], f_s[4], swzx_st[4];
    #pragma unroll
    for (int s = 0; s < 4; ++s) {
        int u   = tid + s * 512;
        tl_s[s] = u >> 9;
        int rem = u & 511;
        jj_s[s] = (rem >> 4) * 2;
        f_s[s]  = (rem & 15) * 4;
        swzx_st[s] = ((f_s[s] >> 2) & 7) << 4;
    }

    // in-flight tile registers
    f32x4 ra0, ra1, rc0[KC], rc1[KC], rx0[4], rx1[4];

    auto load_tile = [&](int j0) {
        const float* ap = attB + (size_t)(i_base + r_a) * NN + j0 + g_a * 8;
        ra0 = *reinterpret_cast<const f32x4*>(ap);
        ra1 = *reinterpret_cast<const f32x4*>(ap + 4);
        #pragma unroll
        for (int k = 0; k < KC; ++k) {
            const float* cp = cheb + ((size_t)k * NN + i_base + r_a) * NN + j0 + g_a * 8;
            rc0[k] = *reinterpret_cast<const f32x4*>(cp);
            rc1[k] = *reinterpret_cast<const f32x4*>(cp + 4);
        }
        #pragma unroll
        for (int s = 0; s < 4; ++s) {
            const float* xp = xB + ((size_t)(t_base + tl_s[s]) * NN + j0 + jj_s[s]) * FF + f_s[s];
            rx0[s] = *reinterpret_cast<const f32x4*>(xp);
            rx1[s] = *reinterpret_cast<const f32x4*>(xp + FF);
        }
    };

    auto store_A = [&](char* Ab) {
        #pragma unroll
        for (int k = 0; k < KC; ++k) {
            bf16x8 w;
            #pragma unroll
            for (int e = 0; e < 4; ++e) {
                w[e]     = (__bf16)(rc0[k][e] * ra0[e]);
                w[e + 4] = (__bf16)(rc1[k][e] * ra1[e]);
            }
            *reinterpret_cast<bf16x8*>(Ab + (k * 64 + r_a) * 128 + ((g_a * 16) ^ swza_st)) = w;
        }
    };

    auto store_X = [&](char* Xb) {
        #pragma unroll
        for (int s = 0; s < 4; ++s) {
            const int c0     = tl_s[s] * 64 + f_s[s];
            const int coloff = (jj_s[s] * 2) ^ swzx_st[s];
            #pragma unroll
            for (int e = 0; e < 4; ++e) {
                union { __bf16 h[2]; unsigned u32; } pk;
                pk.h[0] = (__bf16)rx0[s][e];
                pk.h[1] = (__bf16)rx1[s][e];
                *reinterpret_cast<unsigned*>(Xb + (c0 + e) * 128 + coloff) = pk.u32;
            }
        }
    };

    f32x16 acc[KC][2] = {};
    const int xrow0 = (wm * 64 + l31) * 128;
    const int xrow1 = xrow0 + 32 * 128;
    const int arow  = (wn * 32 + l31) * 128;

    auto phase = [&](const char* AbR, const char* XbR, int kk) {
        const int off = ((kk * 2 + lg) ^ sw3) << 4;
        bf16x8 af0 = *reinterpret_cast<const bf16x8*>(XbR + xrow0 + off);
        bf16x8 af1 = *reinterpret_cast<const bf16x8*>(XbR + xrow1 + off);
        bf16x8 b0  = *reinterpret_cast<const bf16x8*>(AbR + arow + off);
        bf16x8 b1  = *reinterpret_cast<const bf16x8*>(AbR + 8192 + arow + off);
        bf16x8 b2  = *reinterpret_cast<const bf16x8*>(AbR + 16384 + arow + off);
        __builtin_amdgcn_s_setprio(1);
        acc[0][0] = MFMA_B(af0, b0, acc[0][0]); acc[0][1] = MFMA_B(af1, b0, acc[0][1]);
        acc[1][0] = MFMA_B(af0, b1, acc[1][0]); acc[1][1] = MFMA_B(af1, b1, acc[1][1]);
        acc[2][0] = MFMA_B(af0, b2, acc[2][0]); acc[2][1] = MFMA_B(af1, b2, acc[2][1]);
        __builtin_amdgcn_s_setprio(0);
    };

    // prologue: stage tile 0, issue tile-1 loads, one barrier
    load_tile(0);
    store_A(Ab0);
    store_X(Xb0);
    load_tile(64);
    asm volatile("s_waitcnt lgkmcnt(0)" ::: "memory");
    __builtin_amdgcn_s_barrier();

    // main loop: 1 raw barrier per j-tile (no vmcnt drain), 4 MFMA phases,
    // stores + next-load interleaved between phases into the opposite buffer
    for (int jt2 = 0; jt2 < 8; ++jt2) {
        const int jt = jt2 * 2;
        // even tile: read buf0, stage tile jt+1 into buf1
        phase(Ab0, Xb0, 0);
        phase(Ab0, Xb0, 1);
        store_A(Ab1);                       // jt <= 14 always
        phase(Ab0, Xb0, 2);
        store_X(Xb1);
        phase(Ab0, Xb0, 3);
        if (jt + 2 < 16) load_tile((jt + 2) * 64);
        asm volatile("s_waitcnt lgkmcnt(0)" ::: "memory");
        __builtin_amdgcn_s_barrier();

        // odd tile: read buf1, stage tile jt+2 into buf0
        phase(Ab1, Xb1, 0);
        phase(Ab1, Xb1, 1);
        if (jt + 1 < 15) store_A(Ab0);
        phase(Ab1, Xb1, 2);
        if (jt + 1 < 15) store_X(Xb0);
        phase(Ab1, Xb1, 3);
        if (jt + 3 < 16) load_tile((jt + 3) * 64);
        asm volatile("s_waitcnt lgkmcnt(0)" ::: "memory");
        __builtin_amdgcn_s_barrier();
    }

    // ---- stage Theta fragments into buf0 A-region (24576 B exactly) ----
    {
        const int fi0 = wid * 3;
        #pragma unroll
        for (int q = 0; q < 3; ++q) {
            int fi = fi0 + q;
            int k  = fi >> 3;
            int mo = (fi >> 2) & 1;
            int s  = fi & 3;
            int o  = 32 * mo + l31;
            int fb = 32 * (s >> 1) + 16 * (s & 1) + 4 * lg;
            bf16x8 v;
            #pragma unroll
            for (int e = 0; e < 8; ++e) {
                int f = fb + (e & 3) + 8 * (e >> 2);
                v[e] = (__bf16)Theta[(k * FF + f) * FF + o];
            }
            *reinterpret_cast<bf16x8*>(lds_raw + (fi * 64 + lane) * 16) = v;
        }
    }
    __syncthreads();

    // ---- epilogue: out[i][o] = sum_{k,f} rhsT[f][i]^T * Theta ----
    f32x16 of[2] = {};
    #pragma unroll
    for (int k = 0; k < KC; ++k) {
        #pragma unroll
        for (int s = 0; s < 4; ++s) {
            bf16x8 pb;
            #pragma unroll
            for (int e = 0; e < 8; ++e)
                pb[e] = (__bf16)acc[k][s >> 1][e + 8 * (s & 1)];
            #pragma unroll
            for (int mo = 0; mo < 2; ++mo) {
                bf16x8 th = *reinterpret_cast<const bf16x8*>(
                    lds_raw + ((((k * 2 + mo) * 4 + s) * 64) + lane) * 16);
                of[mo] = MFMA_B(pb, th, of[mo]);
            }
        }
    }

    // ---- write out[b, t, i, o] = relu(...), o = lane -> coalesced ----
    const int t = t_base + wm;
    float* op = out + (((size_t)b * TT + t) * NN + i_base + wn * 32) * FF;
    #pragma unroll
    for (int mo = 0; mo < 2; ++mo) {
        #pragma unroll
        for (int r = 0; r < 16; ++r) {
            int row = (r & 3) + 8 * (r >> 2) + 4 * lg;
            int o   = 32 * mo + l31;
            float v = of[mo][r];
            op[(size_t)row * FF + o] = v > 0.0f ? v : 0.0f;
        }
    }
}

extern "C" void kernel_launch(void* const* d_in, const int* in_sizes, int n_in,
                              void* d_out, int out_size, void* d_ws, size_t ws_size,
                              hipStream_t stream) {
    const float* x     = (const float*)d_in[0];
    const float* att   = (const float*)d_in[1];
    const float* cheb  = (const float*)d_in[2];
    const float* Theta = (const float*)d_in[3];
    float* out = (float*)d_out;
    (void)d_ws; (void)ws_size; (void)in_sizes; (void)n_in; (void)out_size;

    dim3 grid(BB * (NN / 64) * (TT / 4));   // 768 blocks
    cheb_fused<<<grid, 512, 0, stream>>>(x, att, cheb, Theta, out);
}